// Round 13
// baseline (105.451 us; speedup 1.0000x reference)
//
#include <hip/hip_runtime.h>
#include <hip/hip_bf16.h>
#include <cstdint>

// MultiRelationalGraphDiffusion: out = LeakyReLU( sum_k conv_w[k] * (adj_norm^k @ (h@W^T)) + conv_b )
// B=8, N=2048, D=256, K=4.
//
// Round-13: diffuse on mfma_f32_32x32x16_fp8_fp8. R12 lesson: 1 vs 2 blk/CU equal ->
// per-CU-resource-bound; LDS-read (2.6 MB/CU/step ~ 8.5us) co-binds with MFMA (8.4us).
// 32x32x16 doubles FLOP/LDS-byte (32768 FLOP / 1KB operands); wave = 32n x 64o amortizes
// A over 2 B-frags -> 42.7 FLOP/B -> LDS 5.1us < MFMA floor.
// Tile 64n x 256o (A read ONCE), BK=128, 8 waves, NBUF=3 (120 KB), R11/R12's proven sync:
// vmcnt(5) -> s_barrier -> stage(t+2 -> buf (t+2)%3) -> compute(t). 5 uniform loads/wave.
// Frags: A (32r x 16k, 512B): lane l = row l&31, k 8*(l>>5)+e. B (16k x 32c): col l&31.
// C/D (m74/m101 verified): col = lane&31, row = (reg&3) + 8*(reg>>2) + 4*(lane>>5).
// b = blockIdx&7 -> batch-per-XCD; c frags written/read on same XCD across steps.
// Scales: adjS=256*adj_norm, cS=16*c -> acc=4096*(adj@c); next cS=acc/256; last tap acc/4096.

#define BATCH 8
#define NN    2048
#define DD    256
#define REPS  1e-9f
#define SLOPE 0.2f

typedef __bf16 bf16x8_t __attribute__((ext_vector_type(8)));
typedef __bf16 bf16x4_t __attribute__((ext_vector_type(4)));
typedef float  f32x4_t  __attribute__((ext_vector_type(4)));
typedef float  f32x16_t __attribute__((ext_vector_type(16)));

__device__ __forceinline__ void gl2lds16(const void* g, void* l) {
    __builtin_amdgcn_global_load_lds(
        (const __attribute__((address_space(1))) unsigned int*)(uintptr_t)g,
        (__attribute__((address_space(3))) unsigned int*)(unsigned int)(uintptr_t)l,
        16, 0, 0);
}

__device__ __forceinline__ unsigned int pk_fp8x4(float a, float b, float c, float d) {
    int lo = __builtin_amdgcn_cvt_pk_fp8_f32(a, b, 0, false);
    return (unsigned int)__builtin_amdgcn_cvt_pk_fp8_f32(c, d, lo, true);
}

__device__ __forceinline__ f32x4_t cvt_f32_fp8x4(unsigned int u) {
    f32x4_t r;
    r[0] = __builtin_amdgcn_cvt_f32_fp8(u, 0);
    r[1] = __builtin_amdgcn_cvt_f32_fp8(u, 1);
    r[2] = __builtin_amdgcn_cvt_f32_fp8(u, 2);
    r[3] = __builtin_amdgcn_cvt_f32_fp8(u, 3);
    return r;
}

// c-frag address, 32x32x16 B-operand layout: frag (ks=n>>4, of=col>>5), lane
// l2 = (col&31) + 32*((n>>3)&1), byte n&7 (n%4==0 -> n&4). 8 of-frags per ks.
__device__ __forceinline__ size_t cfrag32_addr(int b, int n, int col) {
    return ((size_t)(b * 128 + (n >> 4)) * 8 + (col >> 5)) * 512
         + (((col & 31) + 32 * ((n >> 3) & 1)) << 3) + (n & 4);
}

// ================= normadj: 32 rows/block, 32x16 A-frag output via LDS =================
__global__ __launch_bounds__(1024) void k_normadj(const float* __restrict__ adj,
                                                  unsigned char* __restrict__ afrag) {
    __shared__ __align__(16) unsigned char fr[128 * 516];   // 64.5 KB, 516-stride (4-way max)
    const int t = threadIdx.x;
    const int r = t >> 5;          // row-in-block 0..31 (lanes 0-31 = even row of wave)
    const int c = t & 31;          // 64-elem k-chunk
    const int n = blockIdx.x * 32 + r;
    const float* src = adj + (size_t)n * NN + c * 64;
    f32x4_t v[16];
#pragma unroll
    for (int i = 0; i < 16; ++i) v[i] = *(const f32x4_t*)(src + i * 4);
    float s = 0.f;
#pragma unroll
    for (int i = 0; i < 16; ++i) s += v[i][0] + v[i][1] + v[i][2] + v[i][3];
#pragma unroll
    for (int m = 1; m < 32; m <<= 1) s += __shfl_xor(s, m, 64);   // reduce over c (half-wave)
    const float sc = 256.0f / (s + REPS);
    // scatter: d-th 8-byte group -> frag 4c+(d>>1), lane r+32*(d&1), bytes 0..7
#pragma unroll
    for (int d = 0; d < 8; ++d) {
        unsigned char* p = fr + (4 * c + (d >> 1)) * 516 + ((r + 32 * (d & 1)) << 3);
        *(unsigned int*)p =
            pk_fp8x4(v[2 * d][0] * sc, v[2 * d][1] * sc, v[2 * d][2] * sc, v[2 * d][3] * sc);
        *(unsigned int*)(p + 4) =
            pk_fp8x4(v[2 * d + 1][0] * sc, v[2 * d + 1][1] * sc,
                     v[2 * d + 1][2] * sc, v[2 * d + 1][3] * sc);
    }
    __syncthreads();
    // copy out: wave w -> frags [8w, 8w+8), 512B coalesced
    const int w = t >> 6, l = t & 63;
    unsigned char* dst = afrag + (size_t)blockIdx.x * 65536;
#pragma unroll
    for (int f2 = 0; f2 < 8; ++f2) {
        const int f = w * 8 + f2;
        uint2 u;
        u.x = *(const unsigned int*)(fr + f * 516 + l * 8);
        u.y = *(const unsigned int*)(fr + f * 516 + l * 8 + 4);
        *(uint2*)(dst + f * 512 + l * 8) = u;
    }
}

// ================= htrans: bf16x3 MFMA; t_h fp16, c0 in 32x32-B-frag layout =================
__device__ __forceinline__ void pair_remap(int& n0, int& o0, int& b) {
    const int p = blockIdx.x + 32 * (blockIdx.y + 2 * blockIdx.z);
    const int g = p >> 4, r = p & 15;
    o0 = (r >> 3) * 128;
    const int nb = g * 8 + (r & 7);
    n0 = (nb & 31) * 64;
    b  = nb >> 5;
}

__global__ __launch_bounds__(256) void k_htrans(const float* __restrict__ h,
                                                const float* __restrict__ W,
                                                _Float16* __restrict__ t_h,
                                                unsigned char* __restrict__ c0f) {
    __shared__ __align__(16) __bf16 Ah[64 * 64], Al[64 * 64];
    __shared__ __align__(16) __bf16 Bh[128 * 64], Bl[128 * 64];

    const int tid = threadIdx.x;
    int n0, o0, b;
    pair_remap(n0, o0, b);
    const int lane = tid & 63, wv = tid >> 6;
    const int wr = wv >> 1, wc = wv & 1;
    const int rl = lane & 15, kq = lane >> 4;
    const int ar = tid >> 4, ac = (tid & 15) * 4;

    f32x4_t acc[2][4];
#pragma unroll
    for (int i = 0; i < 2; ++i)
#pragma unroll
        for (int j = 0; j < 4; ++j) acc[i][j] = (f32x4_t){0.f, 0.f, 0.f, 0.f};

    for (int kt = 0; kt < 4; ++kt) {
        const int k0 = kt * 64;
#pragma unroll
        for (int q = 0; q < 4; ++q) {
            const int r = q * 16 + ar;
            f32x4_t v = *(const f32x4_t*)(h + ((size_t)b * NN + n0 + r) * DD + k0 + ac);
            bf16x4_t hi4, lo4;
#pragma unroll
            for (int e = 0; e < 4; ++e) {
                float x = v[e];
                __bf16 hh = (__bf16)x;
                hi4[e] = hh;
                lo4[e] = (__bf16)(x - (float)hh);
            }
            const int off = r * 128 + (((ac >> 3) ^ (r & 7)) << 4) + (ac & 7) * 2;
            *(bf16x4_t*)((char*)Ah + off) = hi4;
            *(bf16x4_t*)((char*)Al + off) = lo4;
        }
#pragma unroll
        for (int q = 0; q < 8; ++q) {
            const int r = q * 16 + ar;
            f32x4_t v = *(const f32x4_t*)(W + (size_t)(o0 + r) * DD + k0 + ac);
            bf16x4_t hi4, lo4;
#pragma unroll
            for (int e = 0; e < 4; ++e) {
                float x = v[e];
                __bf16 hh = (__bf16)x;
                hi4[e] = hh;
                lo4[e] = (__bf16)(x - (float)hh);
            }
            const int off = r * 128 + (((ac >> 3) ^ (r & 7)) << 4) + (ac & 7) * 2;
            *(bf16x4_t*)((char*)Bh + off) = hi4;
            *(bf16x4_t*)((char*)Bl + off) = lo4;
        }
        __syncthreads();
#pragma unroll
        for (int s = 0; s < 2; ++s) {
            bf16x8_t ah[2], al[2], bh[4], bl[4];
#pragma unroll
            for (int i = 0; i < 2; ++i) {
                const int row = wr * 32 + i * 16 + rl;
                const int byo = row * 128 + (((s * 4 + kq) ^ (row & 7)) << 4);
                ah[i] = *(const bf16x8_t*)((const char*)Ah + byo);
                al[i] = *(const bf16x8_t*)((const char*)Al + byo);
            }
#pragma unroll
            for (int j = 0; j < 4; ++j) {
                const int o = wc * 64 + j * 16 + rl;
                const int byo = o * 128 + (((s * 4 + kq) ^ (o & 7)) << 4);
                bh[j] = *(const bf16x8_t*)((const char*)Bh + byo);
                bl[j] = *(const bf16x8_t*)((const char*)Bl + byo);
            }
#pragma unroll
            for (int i = 0; i < 2; ++i)
#pragma unroll
                for (int j = 0; j < 4; ++j) {
                    acc[i][j] = __builtin_amdgcn_mfma_f32_16x16x32_bf16(ah[i], bh[j], acc[i][j], 0, 0, 0);
                    acc[i][j] = __builtin_amdgcn_mfma_f32_16x16x32_bf16(al[i], bh[j], acc[i][j], 0, 0, 0);
                    acc[i][j] = __builtin_amdgcn_mfma_f32_16x16x32_bf16(ah[i], bl[j], acc[i][j], 0, 0, 0);
                }
        }
        __syncthreads();
    }

#pragma unroll
    for (int i = 0; i < 2; ++i)
#pragma unroll
        for (int j = 0; j < 4; ++j) {
            const int row0 = n0 + wr * 32 + i * 16 + kq * 4;
            const int col  = o0 + wc * 64 + j * 16 + rl;
            _Float16* tp = t_h + ((size_t)b * NN + row0) * DD + col;
#pragma unroll
            for (int r2 = 0; r2 < 4; ++r2) tp[r2 * DD] = (_Float16)acc[i][j][r2];
            *(unsigned int*)(c0f + cfrag32_addr(b, row0, col)) =
                pk_fp8x4(16.f * acc[i][j][0], 16.f * acc[i][j][1],
                         16.f * acc[i][j][2], 16.f * acc[i][j][3]);
        }
}

// ================= diffuse: 32x32x16 fp8 MFMA, frag-major LDS, counted vmcnt =================
// tile 64n x 256o, BK=128, 512 thr / 8 waves (wr 0..1 x wc 0..3), wave = 32n x 64o.
// LDS/buffer: A 16 frags [nf][ks] = 8 KB; B 64 frags [ks][of] = 32 KB. NBUF=3 -> 120 KB.
template <bool LAST>
__global__ __launch_bounds__(512) void k_diffuse(const unsigned char* __restrict__ afrag,
                                                 const unsigned char* __restrict__ cin,
                                                 unsigned char* __restrict__ cout,
                                                 const unsigned char* __restrict__ c1f,
                                                 const unsigned char* __restrict__ c2f,
                                                 const _Float16* __restrict__ t_h,
                                                 float* __restrict__ out,
                                                 const float* __restrict__ convw,
                                                 const float* __restrict__ convb) {
    __shared__ __align__(16) unsigned char As[3][8192];    // 24 KB
    __shared__ __align__(16) unsigned char Bs[3][32768];   // 96 KB

    const int tid = threadIdx.x;
    const int p = blockIdx.x;
    const int b = p & 7;              // batch = XCD
    const int n0 = (p >> 3) * 64;

    const int lane = tid & 63, wv = tid >> 6;
    const int wr = wv >> 2, wc = wv & 3;
    const int lc = lane & 31, lh = lane >> 5;

    // staging: per tile, wave wv issues 1 A-load (frag pair) + 4 B-loads (1 KB each)
    const unsigned char* aSrc = afrag
        + ((size_t)((b * 64 + (n0 >> 5) + (wv >> 2)) * 128) + (wv & 3) * 2) * 512 + lane * 16;
    const unsigned char* cSrc = cin + (size_t)b * 524288 + wv * 4096 + lane * 16;

    f32x16_t acc[2];
#pragma unroll
    for (int j = 0; j < 2; ++j)
#pragma unroll
        for (int e = 0; e < 16; ++e) acc[j][e] = 0.f;

#define STAGE(T, BUF)                                                                  \
    {                                                                                  \
        const int tt = (T) & 15;                                                       \
        gl2lds16(aSrc + (size_t)tt * 4096, As[BUF] + (wv >> 2) * 4096 + (wv & 3) * 1024); \
        const unsigned char* cs = cSrc + (size_t)tt * 32768;                           \
        gl2lds16(cs,        Bs[BUF] + wv * 4096);                                      \
        gl2lds16(cs + 1024, Bs[BUF] + wv * 4096 + 1024);                               \
        gl2lds16(cs + 2048, Bs[BUF] + wv * 4096 + 2048);                               \
        gl2lds16(cs + 3072, Bs[BUF] + wv * 4096 + 3072);                               \
    }

    STAGE(0, 0)
    STAGE(1, 1)

    int bc = 0, bs = 2;   // compute buf = t%3, stage buf = (t+2)%3
    for (int t = 0; t < 16; ++t) {
        asm volatile("s_waitcnt vmcnt(5)" ::: "memory");   // tile t's 5 loads landed
        __builtin_amdgcn_s_barrier();                      // all waves' tile-t loads landed
        __builtin_amdgcn_sched_barrier(0);
        STAGE(t + 2, bs)                                   // safe: all finished compute(t-1)
        __builtin_amdgcn_sched_barrier(0);
        const unsigned char* Ac = As[bc] + wr * 4096;
        const unsigned char* Bc = Bs[bc];
#pragma unroll
        for (int ks = 0; ks < 8; ++ks) {
            long a  = *(const long*)(Ac + ks * 512 + lane * 8);
            long b0 = *(const long*)(Bc + ks * 4096 + (wc * 2) * 512 + lane * 8);
            long b1 = *(const long*)(Bc + ks * 4096 + (wc * 2 + 1) * 512 + lane * 8);
            acc[0] = __builtin_amdgcn_mfma_f32_32x32x16_fp8_fp8(a, b0, acc[0], 0, 0, 0);
            acc[1] = __builtin_amdgcn_mfma_f32_32x32x16_fp8_fp8(a, b1, acc[1], 0, 0, 0);
        }
        bc = (bc == 2) ? 0 : bc + 1;
        bs = (bs == 2) ? 0 : bs + 1;
    }
#undef STAGE

    // ---- epilogue: D col = 32*(2wc+j) + lc; rows (per reg 4g+r2) = n0+32wr+8g+4lh+r2 ----
#pragma unroll
    for (int j = 0; j < 2; ++j) {
        const int col = (wc * 2 + j) * 32 + lc;
#pragma unroll
        for (int g = 0; g < 4; ++g) {
            const int n = n0 + wr * 32 + g * 8 + lh * 4;
            if (LAST) {
                const float cw0 = convw[0], cw1 = convw[1], cw2 = convw[2], cw3 = convw[3];
                const float cb  = convb[0];
                const float ru = 1.0f / 16.0f, rf = 1.0f / 4096.0f;
                float* op = out + ((size_t)b * NN + n) * DD + col;
                const _Float16* tp = t_h + ((size_t)b * NN + n) * DD + col;
                const size_t sa = cfrag32_addr(b, n, col);
                f32x4_t u1 = cvt_f32_fp8x4(*(const unsigned int*)(c1f + sa));
                f32x4_t u2 = cvt_f32_fp8x4(*(const unsigned int*)(c2f + sa));
#pragma unroll
                for (int r2 = 0; r2 < 4; ++r2) {
                    float v = cw0 * (float)tp[r2 * DD] + cw1 * ru * u1[r2] + cw2 * ru * u2[r2]
                            + cw3 * rf * acc[j][4 * g + r2] + cb;
                    op[r2 * DD] = v >= 0.0f ? v : SLOPE * v;
                }
            } else {
                const float rs = 1.0f / 256.0f;   // acc -> 16*c_next
                *(unsigned int*)(cout + cfrag32_addr(b, n, col)) =
                    pk_fp8x4(rs * acc[j][4 * g], rs * acc[j][4 * g + 1],
                             rs * acc[j][4 * g + 2], rs * acc[j][4 * g + 3]);
            }
        }
    }
}

extern "C" void kernel_launch(void* const* d_in, const int* in_sizes, int n_in,
                              void* d_out, int out_size, void* d_ws, size_t ws_size,
                              hipStream_t stream) {
    const float* h   = (const float*)d_in[0];
    const float* adj = (const float*)d_in[1];
    const float* W   = (const float*)d_in[2];
    const float* cw  = (const float*)d_in[3];
    const float* cb  = (const float*)d_in[4];
    float* out = (float*)d_out;

    char* ws = (char*)d_ws;
    unsigned char* afrag = (unsigned char*)ws;                        // 32 MB
    unsigned char* c0f   = (unsigned char*)(ws + 33554432);           // 4 MB
    unsigned char* c1f   = (unsigned char*)(ws + 37748736);           // 4 MB
    unsigned char* c2f   = (unsigned char*)(ws + 41943040);           // 4 MB
    _Float16*      t_h   = (_Float16*)(ws + 46137344);                // 8.4 MB (~52.5 MB)

    k_normadj<<<BATCH * NN / 32, 1024, 0, stream>>>(adj, afrag);
    k_htrans<<<dim3(32, 2, BATCH), 256, 0, stream>>>(h, W, t_h, c0f);
    k_diffuse<false><<<256, 512, 0, stream>>>(afrag, c0f, c1f, nullptr, nullptr, nullptr, out, cw, cb);
    k_diffuse<false><<<256, 512, 0, stream>>>(afrag, c1f, c2f, nullptr, nullptr, nullptr, out, cw, cb);
    k_diffuse<true ><<<256, 512, 0, stream>>>(afrag, c2f, nullptr, c1f, c2f, t_h, out, cw, cb);
}

// Round 14
// 101.787 us; speedup vs baseline: 1.0360x; 1.0360x over previous
//
#include <hip/hip_runtime.h>
#include <hip/hip_bf16.h>
#include <cstdint>

// MultiRelationalGraphDiffusion: out = LeakyReLU( sum_k conv_w[k] * (adj_norm^k @ (h@W^T)) + conv_b )
// B=8, N=2048, D=256, K=4.
//
// Round-14 = R12 (best, 102.5us) + diffuse block remap: batch-per-XCD (b = p&7 -> the
// c-operand chain written in step k / read in step k+1 stays on ONE XCD's L2; adjq batch
// slice ~4MB L2-resident after first read) + oh-pairing (o-halves 8 IDs apart -> shared
// A-rows L2-hit) + s_setprio(1) around the MFMA cluster (T5; free, phase-diverse waves).
// R13 lesson: 32x32x16 shape was neutral->negative; diffuse is bound by the SUM of
// MFMA/LDS/L2/sync, not one axis. This round removes the cross-XCD L3 round trips.
// Scales: adjS=256*adj_norm, cS=16*c -> acc=4096*(adj@c); next cS=acc/256; last tap acc/4096.

#define BATCH 8
#define NN    2048
#define DD    256
#define REPS  1e-9f
#define SLOPE 0.2f

typedef __bf16 bf16x8_t __attribute__((ext_vector_type(8)));
typedef __bf16 bf16x4_t __attribute__((ext_vector_type(4)));
typedef float  f32x4_t  __attribute__((ext_vector_type(4)));

__device__ __forceinline__ void gl2lds16(const void* g, void* l) {
    __builtin_amdgcn_global_load_lds(
        (const __attribute__((address_space(1))) unsigned int*)(uintptr_t)g,
        (__attribute__((address_space(3))) unsigned int*)(unsigned int)(uintptr_t)l,
        16, 0, 0);
}

__device__ __forceinline__ unsigned int pk_fp8x4(float a, float b, float c, float d) {
    int lo = __builtin_amdgcn_cvt_pk_fp8_f32(a, b, 0, false);
    return (unsigned int)__builtin_amdgcn_cvt_pk_fp8_f32(c, d, lo, true);
}

__device__ __forceinline__ f32x4_t cvt_f32_fp8x4(unsigned int u) {
    f32x4_t r;
    r[0] = __builtin_amdgcn_cvt_f32_fp8(u, 0);
    r[1] = __builtin_amdgcn_cvt_f32_fp8(u, 1);
    r[2] = __builtin_amdgcn_cvt_f32_fp8(u, 2);
    r[3] = __builtin_amdgcn_cvt_f32_fp8(u, 3);
    return r;
}

__device__ __forceinline__ uint2 q8(f32x4_t a, f32x4_t b, float sc) {
    uint2 r;
    r.x = pk_fp8x4(a[0] * sc, a[1] * sc, a[2] * sc, a[3] * sc);
    r.y = pk_fp8x4(b[0] * sc, b[1] * sc, b[2] * sc, b[3] * sc);
    return r;
}

// c-frag address (verified R10-R12)
__device__ __forceinline__ size_t cfrag_addr(int b, int row0, int col) {
    return ((size_t)(b * 64 + (row0 >> 5)) * 16 + (col >> 4)) * 512
         + ((col & 15) + 16 * ((row0 >> 3) & 3)) * 8 + (row0 & 4);
}

// ================= normadj: frag-major output via LDS transpose (verified R10-R12) =================
__global__ __launch_bounds__(1024) void k_normadj(const float* __restrict__ adj,
                                                  unsigned char* __restrict__ afrag) {
    __shared__ __align__(16) unsigned char fr[64 * 520];
    const int w = threadIdx.x >> 6;
    const int l = threadIdx.x & 63;
    const int n = blockIdx.x * 16 + w;
    const float* src = adj + (size_t)n * NN;
    f32x4_t v[8];
#pragma unroll
    for (int q = 0; q < 4; ++q) {
        v[2 * q]     = *(const f32x4_t*)(src + q * 512 + l * 8);
        v[2 * q + 1] = *(const f32x4_t*)(src + q * 512 + l * 8 + 4);
    }
    float s = 0.f;
#pragma unroll
    for (int j = 0; j < 8; ++j) s += v[j][0] + v[j][1] + v[j][2] + v[j][3];
#pragma unroll
    for (int m = 1; m < 64; m <<= 1) s += __shfl_xor(s, m, 64);
    const float sc = 256.0f / (s + REPS);
#pragma unroll
    for (int q = 0; q < 4; ++q) {
        uint2 u = q8(v[2 * q], v[2 * q + 1], sc);
        *(uint2*)(fr + (16 * q + (l >> 2)) * 520 + w * 8 + (l & 3) * 128) = u;
    }
    __syncthreads();
    unsigned char* dst = afrag + (size_t)blockIdx.x * 64 * 512;
#pragma unroll
    for (int f2 = 0; f2 < 4; ++f2) {
        const int f = w * 4 + f2;
        *(uint2*)(dst + (size_t)f * 512 + l * 8) = *(const uint2*)(fr + f * 520 + l * 8);
    }
}

// ================= htrans: bf16x3 MFMA; t_h fp16, c0 frag-major (verified R10-R12) =================
__device__ __forceinline__ void pair_remap(int& n0, int& o0, int& b) {
    const int p = blockIdx.x + 32 * (blockIdx.y + 2 * blockIdx.z);
    const int g = p >> 4, r = p & 15;
    o0 = (r >> 3) * 128;
    const int nb = g * 8 + (r & 7);
    n0 = (nb & 31) * 64;
    b  = nb >> 5;
}

__global__ __launch_bounds__(256) void k_htrans(const float* __restrict__ h,
                                                const float* __restrict__ W,
                                                _Float16* __restrict__ t_h,
                                                unsigned char* __restrict__ c0f) {
    __shared__ __align__(16) __bf16 Ah[64 * 64], Al[64 * 64];
    __shared__ __align__(16) __bf16 Bh[128 * 64], Bl[128 * 64];

    const int tid = threadIdx.x;
    int n0, o0, b;
    pair_remap(n0, o0, b);
    const int lane = tid & 63, wv = tid >> 6;
    const int wr = wv >> 1, wc = wv & 1;
    const int rl = lane & 15, kq = lane >> 4;
    const int ar = tid >> 4, ac = (tid & 15) * 4;

    f32x4_t acc[2][4];
#pragma unroll
    for (int i = 0; i < 2; ++i)
#pragma unroll
        for (int j = 0; j < 4; ++j) acc[i][j] = (f32x4_t){0.f, 0.f, 0.f, 0.f};

    for (int kt = 0; kt < 4; ++kt) {
        const int k0 = kt * 64;
#pragma unroll
        for (int q = 0; q < 4; ++q) {
            const int r = q * 16 + ar;
            f32x4_t v = *(const f32x4_t*)(h + ((size_t)b * NN + n0 + r) * DD + k0 + ac);
            bf16x4_t hi4, lo4;
#pragma unroll
            for (int e = 0; e < 4; ++e) {
                float x = v[e];
                __bf16 hh = (__bf16)x;
                hi4[e] = hh;
                lo4[e] = (__bf16)(x - (float)hh);
            }
            const int off = r * 128 + (((ac >> 3) ^ (r & 7)) << 4) + (ac & 7) * 2;
            *(bf16x4_t*)((char*)Ah + off) = hi4;
            *(bf16x4_t*)((char*)Al + off) = lo4;
        }
#pragma unroll
        for (int q = 0; q < 8; ++q) {
            const int r = q * 16 + ar;
            f32x4_t v = *(const f32x4_t*)(W + (size_t)(o0 + r) * DD + k0 + ac);
            bf16x4_t hi4, lo4;
#pragma unroll
            for (int e = 0; e < 4; ++e) {
                float x = v[e];
                __bf16 hh = (__bf16)x;
                hi4[e] = hh;
                lo4[e] = (__bf16)(x - (float)hh);
            }
            const int off = r * 128 + (((ac >> 3) ^ (r & 7)) << 4) + (ac & 7) * 2;
            *(bf16x4_t*)((char*)Bh + off) = hi4;
            *(bf16x4_t*)((char*)Bl + off) = lo4;
        }
        __syncthreads();
#pragma unroll
        for (int s = 0; s < 2; ++s) {
            bf16x8_t ah[2], al[2], bh[4], bl[4];
#pragma unroll
            for (int i = 0; i < 2; ++i) {
                const int row = wr * 32 + i * 16 + rl;
                const int byo = row * 128 + (((s * 4 + kq) ^ (row & 7)) << 4);
                ah[i] = *(const bf16x8_t*)((const char*)Ah + byo);
                al[i] = *(const bf16x8_t*)((const char*)Al + byo);
            }
#pragma unroll
            for (int j = 0; j < 4; ++j) {
                const int o = wc * 64 + j * 16 + rl;
                const int byo = o * 128 + (((s * 4 + kq) ^ (o & 7)) << 4);
                bh[j] = *(const bf16x8_t*)((const char*)Bh + byo);
                bl[j] = *(const bf16x8_t*)((const char*)Bl + byo);
            }
#pragma unroll
            for (int i = 0; i < 2; ++i)
#pragma unroll
                for (int j = 0; j < 4; ++j) {
                    acc[i][j] = __builtin_amdgcn_mfma_f32_16x16x32_bf16(ah[i], bh[j], acc[i][j], 0, 0, 0);
                    acc[i][j] = __builtin_amdgcn_mfma_f32_16x16x32_bf16(al[i], bh[j], acc[i][j], 0, 0, 0);
                    acc[i][j] = __builtin_amdgcn_mfma_f32_16x16x32_bf16(ah[i], bl[j], acc[i][j], 0, 0, 0);
                }
        }
        __syncthreads();
    }

#pragma unroll
    for (int i = 0; i < 2; ++i)
#pragma unroll
        for (int j = 0; j < 4; ++j) {
            const int row0 = n0 + wr * 32 + i * 16 + kq * 4;
            const int col  = o0 + wc * 64 + j * 16 + rl;
            _Float16* tp = t_h + ((size_t)b * NN + row0) * DD + col;
#pragma unroll
            for (int r2 = 0; r2 < 4; ++r2) tp[r2 * DD] = (_Float16)acc[i][j][r2];
            *(unsigned int*)(c0f + cfrag_addr(b, row0, col)) =
                pk_fp8x4(16.f * acc[i][j][0], 16.f * acc[i][j][1],
                         16.f * acc[i][j][2], 16.f * acc[i][j][3]);
        }
}

// ================= diffuse: frag-major LDS, o-split, batch-per-XCD, counted vmcnt =================
// tile 64n x 128o, BK=128, 512 thr / 8 waves (wr 0..3 x wc 0..1), wave = 16 x 64.
// NBUF=3 -> 72 KB -> 2 blocks/CU. 3 loads/wave/tile (1 A + 2 B). Sync proven R11/R12.
// Remap: b = p&7 (batch = XCD; c chain + adjq slice L2-local), oh-pair 8 IDs apart.
template <bool LAST>
__global__ __launch_bounds__(512) void k_diffuse(const unsigned char* __restrict__ afrag,
                                                 const unsigned char* __restrict__ cin,
                                                 unsigned char* __restrict__ cout,
                                                 const unsigned char* __restrict__ c1f,
                                                 const unsigned char* __restrict__ c2f,
                                                 const _Float16* __restrict__ t_h,
                                                 float* __restrict__ out,
                                                 const float* __restrict__ convw,
                                                 const float* __restrict__ convb) {
    __shared__ __align__(16) unsigned char As[3][8192];    // 24 KB
    __shared__ __align__(16) unsigned char Bs[3][16384];   // 48 KB

    const int tid = threadIdx.x;
    // batch-per-XCD remap: b = p&7; o-halves of one (n0,b) are 8 IDs apart (same XCD)
    const int p = blockIdx.x;
    const int b  = p & 7;
    const int oh = (p >> 3) & 1;
    const int n0 = (p >> 4) * 64;

    const int lane = tid & 63, wv = tid >> 6;
    const int wr = wv >> 1, wc = wv & 1;
    const int rl = lane & 15, kq = lane >> 4;

    // staging sources: wave wv -> A frag group nfl=wr (half wv&1), B ks-group ksl=wr
    const unsigned char* aSrc = afrag
        + ((size_t)(b * 128 + (n0 >> 4) + wr) * 64) * 512 + (wv & 1) * 1024 + lane * 16;
    const unsigned char* cSrc = cin
        + ((size_t)(b * 64) * 16 + oh * 8) * 512 + (wv & 1) * 2048 + lane * 16;

    f32x4_t acc[4];
#pragma unroll
    for (int j = 0; j < 4; ++j) acc[j] = (f32x4_t){0.f, 0.f, 0.f, 0.f};

#define STAGE(T, BUF)                                                                  \
    {                                                                                  \
        const int tt = (T) & 15;                                                       \
        gl2lds16(aSrc + (size_t)tt * 2048, As[BUF] + wr * 2048 + (wv & 1) * 1024);     \
        const unsigned char* cs = cSrc + (size_t)(tt * 4 + wr) * 8192;                 \
        gl2lds16(cs, Bs[BUF] + wr * 4096 + (wv & 1) * 2048);                           \
        gl2lds16(cs + 1024, Bs[BUF] + wr * 4096 + (wv & 1) * 2048 + 1024);             \
    }

    STAGE(0, 0)
    STAGE(1, 1)

    int bc = 0, bs = 2;   // compute buf = t%3, stage buf = (t+2)%3
    for (int t = 0; t < 16; ++t) {
        asm volatile("s_waitcnt vmcnt(3)" ::: "memory");   // tile t's 3 loads landed
        __builtin_amdgcn_s_barrier();                      // all waves' tile-t loads landed
        __builtin_amdgcn_sched_barrier(0);
        STAGE(t + 2, bs)                                   // safe: all finished compute(t-1)
        __builtin_amdgcn_sched_barrier(0);
        const unsigned char* Ac = As[bc];
        const unsigned char* Bc = Bs[bc];
        __builtin_amdgcn_s_setprio(1);                     // T5: favor MFMA-entering waves
#pragma unroll
        for (int s = 0; s < 4; ++s) {
            long a = *(const long*)(Ac + (wr * 4 + s) * 512 + lane * 8);
            long bb[4];
#pragma unroll
            for (int j = 0; j < 4; ++j)
                bb[j] = *(const long*)(Bc + (s * 8 + wc * 4 + j) * 512 + lane * 8);
#pragma unroll
            for (int j = 0; j < 4; ++j)
                acc[j] = __builtin_amdgcn_mfma_f32_16x16x32_fp8_fp8(a, bb[j], acc[j], 0, 0, 0);
        }
        __builtin_amdgcn_s_setprio(0);
        bc = (bc == 2) ? 0 : bc + 1;
        bs = (bs == 2) ? 0 : bs + 1;
    }
#undef STAGE

    // ---- epilogue: D frag col=lane&15, row=(lane>>4)*4+reg ----
#pragma unroll
    for (int j = 0; j < 4; ++j) {
        const int row0 = n0 + wr * 16 + kq * 4;
        const int col  = oh * 128 + wc * 64 + j * 16 + rl;
        if (LAST) {
            const float cw0 = convw[0], cw1 = convw[1], cw2 = convw[2], cw3 = convw[3];
            const float cb  = convb[0];
            const float ru = 1.0f / 16.0f, rf = 1.0f / 4096.0f;
            float* op = out + ((size_t)b * NN + row0) * DD + col;
            const _Float16* tp = t_h + ((size_t)b * NN + row0) * DD + col;
            const size_t sa = cfrag_addr(b, row0, col);
            f32x4_t u1 = cvt_f32_fp8x4(*(const unsigned int*)(c1f + sa));
            f32x4_t u2 = cvt_f32_fp8x4(*(const unsigned int*)(c2f + sa));
#pragma unroll
            for (int r2 = 0; r2 < 4; ++r2) {
                float v = cw0 * (float)tp[r2 * DD] + cw1 * ru * u1[r2] + cw2 * ru * u2[r2]
                        + cw3 * rf * acc[j][r2] + cb;
                op[r2 * DD] = v >= 0.0f ? v : SLOPE * v;
            }
        } else {
            const float rs = 1.0f / 256.0f;   // acc -> 16*c_next
            *(unsigned int*)(cout + cfrag_addr(b, row0, col)) =
                pk_fp8x4(rs * acc[j][0], rs * acc[j][1], rs * acc[j][2], rs * acc[j][3]);
        }
    }
}

extern "C" void kernel_launch(void* const* d_in, const int* in_sizes, int n_in,
                              void* d_out, int out_size, void* d_ws, size_t ws_size,
                              hipStream_t stream) {
    const float* h   = (const float*)d_in[0];
    const float* adj = (const float*)d_in[1];
    const float* W   = (const float*)d_in[2];
    const float* cw  = (const float*)d_in[3];
    const float* cb  = (const float*)d_in[4];
    float* out = (float*)d_out;

    char* ws = (char*)d_ws;
    unsigned char* afrag = (unsigned char*)ws;                        // 32 MB
    unsigned char* c0f   = (unsigned char*)(ws + 33554432);           // 4 MB
    unsigned char* c1f   = (unsigned char*)(ws + 37748736);           // 4 MB
    unsigned char* c2f   = (unsigned char*)(ws + 41943040);           // 4 MB
    _Float16*      t_h   = (_Float16*)(ws + 46137344);                // 8.4 MB (~52.5 MB)

    k_normadj<<<BATCH * NN / 16, 1024, 0, stream>>>(adj, afrag);
    k_htrans<<<dim3(32, 2, BATCH), 256, 0, stream>>>(h, W, t_h, c0f);
    k_diffuse<false><<<512, 512, 0, stream>>>(afrag, c0f, c1f, nullptr, nullptr, nullptr, out, cw, cb);
    k_diffuse<false><<<512, 512, 0, stream>>>(afrag, c1f, c2f, nullptr, nullptr, nullptr, out, cw, cb);
    k_diffuse<true ><<<512, 512, 0, stream>>>(afrag, c2f, nullptr, c1f, c2f, t_h, out, cw, cb);
}